// Round 9
// baseline (467.712 us; speedup 1.0000x reference)
//
#include <hip/hip_runtime.h>
#include <hip/hip_cooperative_groups.h>

namespace cg = cooperative_groups;

// SoftAttention: B=4, Q=64, S=1024, H=512, fp32.
// out = [context (B*Q*H)] ++ [weights (B*Q*S)]
// ws: qp [256*512] at 0; kp [4096*512] at +512KB; context partials alias kp.
// qp/kp hold (2*log2e)*(X@W+b): score term = exp2(qp+kp) = exp(2*(q+k)).
// Sum(we) and be are (q,s)-independent -> cancel in softmax -> dropped.
// r5 lesson: NO global atomics for partial sums (memory-side RMW).
// r7 lesson: 1 wave/SIMD cannot hide LDS/global latency; keep >=2 waves/SIMD.
// r8 lesson: non-proj time (~130us) is launch/serialization overhead, not
//   compute (score rewrites don't move it) -> single cooperative kernel.

constexpr int kB = 4;
constexpr int kQ = 64;
constexpr int kS = 1024;
constexpr int kH = 512;
constexpr float kScale = 2.8853900817779268f;  // 2*log2(e)
constexpr int kLdsStride = 68;
constexpr int kSmF = 4 * 32 * kLdsStride;  // 8704 floats = 34816 B shared pool

// ---------------------------------------------------------------------------
// Phase 1: projection Y = kScale*(X@W + bias).  544 jobs (8 ct x 68 rt).
// 64x64 tile, 256 thr, 4x4 acc/thread, K-chunks of 32 double-buffered.
// ---------------------------------------------------------------------------
__device__ __forceinline__ void proj_phase(
    int job, float* sm,
    const float* __restrict__ Xk, const float* __restrict__ Wk,
    const float* __restrict__ bk, float* __restrict__ Yk,
    const float* __restrict__ Xq, const float* __restrict__ Wq,
    const float* __restrict__ bq, float* __restrict__ Yq) {
  const int t = threadIdx.x;
  const int ct = job & 7;
  int rt = job >> 3;  // 0..67
  const float *X, *W, *bias;
  float* Y;
  if (rt < 64) {
    X = Xk + (size_t)rt * 64 * kH; W = Wk; bias = bk; Y = Yk + (size_t)rt * 64 * kH;
  } else {
    rt -= 64;
    X = Xq + (size_t)rt * 64 * kH; W = Wq; bias = bq; Y = Yq + (size_t)rt * 64 * kH;
  }

  const int a_row = t & 63;
  const int a_k0 = (t >> 6) * 8;
  const int b_kl = t >> 4;
  const int b_c = (t & 15) * 4;
  const int cbase = ct * 64;
  const int r0 = (t >> 4) * 4;
  const int c0 = (t & 15) * 4;

  float4 pa[2], pb[2];

  auto gload = [&](int kb) {
    const float* xp = X + (size_t)a_row * kH + kb + a_k0;
    pa[0] = *(const float4*)(xp + 0);
    pa[1] = *(const float4*)(xp + 4);
#pragma unroll
    for (int p = 0; p < 2; p++)
      pb[p] = *(const float4*)(W + (size_t)(kb + p * 16 + b_kl) * kH + cbase + b_c);
  };

  auto lwrite = [&](int buf) {
    float* a = sm + buf * (32 * kLdsStride);
#pragma unroll
    for (int j = 0; j < 2; j++) {
      a[(a_k0 + 4 * j + 0) * kLdsStride + a_row] = pa[j].x;
      a[(a_k0 + 4 * j + 1) * kLdsStride + a_row] = pa[j].y;
      a[(a_k0 + 4 * j + 2) * kLdsStride + a_row] = pa[j].z;
      a[(a_k0 + 4 * j + 3) * kLdsStride + a_row] = pa[j].w;
    }
    float* b = sm + 2 * (32 * kLdsStride) + buf * (32 * kLdsStride);
#pragma unroll
    for (int p = 0; p < 2; p++)
      *(float4*)(b + (p * 16 + b_kl) * kLdsStride + b_c) = pb[p];
  };

  float4 acc0 = {0,0,0,0}, acc1 = {0,0,0,0}, acc2 = {0,0,0,0}, acc3 = {0,0,0,0};

  gload(0);
  lwrite(0);
  __syncthreads();

  for (int kc = 0; kc < 16; kc++) {
    if (kc < 15) gload((kc + 1) * 32);

    const float* a = sm + (kc & 1) * (32 * kLdsStride);
    const float* b = sm + 2 * (32 * kLdsStride) + (kc & 1) * (32 * kLdsStride);
#pragma unroll 8
    for (int kk = 0; kk < 32; kk++) {
      float4 av = *(const float4*)(a + kk * kLdsStride + r0);
      float4 bv = *(const float4*)(b + kk * kLdsStride + c0);
      acc0.x = fmaf(av.x, bv.x, acc0.x); acc0.y = fmaf(av.x, bv.y, acc0.y);
      acc0.z = fmaf(av.x, bv.z, acc0.z); acc0.w = fmaf(av.x, bv.w, acc0.w);
      acc1.x = fmaf(av.y, bv.x, acc1.x); acc1.y = fmaf(av.y, bv.y, acc1.y);
      acc1.z = fmaf(av.y, bv.z, acc1.z); acc1.w = fmaf(av.y, bv.w, acc1.w);
      acc2.x = fmaf(av.z, bv.x, acc2.x); acc2.y = fmaf(av.z, bv.y, acc2.y);
      acc2.z = fmaf(av.z, bv.z, acc2.z); acc2.w = fmaf(av.z, bv.w, acc2.w);
      acc3.x = fmaf(av.w, bv.x, acc3.x); acc3.y = fmaf(av.w, bv.y, acc3.y);
      acc3.z = fmaf(av.w, bv.z, acc3.z); acc3.w = fmaf(av.w, bv.w, acc3.w);
    }

    if (kc < 15) {
      __syncthreads();
      lwrite((kc + 1) & 1);
      __syncthreads();
    }
  }

  float4 bv = *(const float4*)(bias + cbase + c0);
  float* yp = Y + (size_t)r0 * kH + cbase + c0;
  float4 o;
  o.x = kScale*(acc0.x+bv.x); o.y = kScale*(acc0.y+bv.y);
  o.z = kScale*(acc0.z+bv.z); o.w = kScale*(acc0.w+bv.w);
  *(float4*)(yp + 0 * kH) = o;
  o.x = kScale*(acc1.x+bv.x); o.y = kScale*(acc1.y+bv.y);
  o.z = kScale*(acc1.z+bv.z); o.w = kScale*(acc1.w+bv.w);
  *(float4*)(yp + 1 * kH) = o;
  o.x = kScale*(acc2.x+bv.x); o.y = kScale*(acc2.y+bv.y);
  o.z = kScale*(acc2.z+bv.z); o.w = kScale*(acc2.w+bv.w);
  *(float4*)(yp + 2 * kH) = o;
  o.x = kScale*(acc3.x+bv.x); o.y = kScale*(acc3.y+bv.y);
  o.z = kScale*(acc3.z+bv.z); o.w = kScale*(acc3.w+bv.w);
  *(float4*)(yp + 3 * kH) = o;
}

// ---------------------------------------------------------------------------
// Phase 2: scores (shifted) -> sout.  LDS-free, 1024 jobs (b x 8 qt x 32 st).
// score' = sum_h (-2*we[h]) * rcp(1 + exp2(qp+kp)); 8 q x 8 s per wave.
// ---------------------------------------------------------------------------
__device__ __forceinline__ void score_phase(
    int job, const float* __restrict__ qp, const float* __restrict__ kp,
    const float* __restrict__ we, float* __restrict__ sout) {
  const int b = job >> 8, qt = (job >> 5) & 7, st = job & 31;
  const int t = threadIdx.x, wave = t >> 6, lane = t & 63;

  const float4* we4 = (const float4*)(we + lane * 8);
  float4 w0 = we4[0], w1 = we4[1];
  w0.x *= -2.f; w0.y *= -2.f; w0.z *= -2.f; w0.w *= -2.f;
  w1.x *= -2.f; w1.y *= -2.f; w1.z *= -2.f; w1.w *= -2.f;

  const int q0 = qt * 8;
  float4 qv[8][2];
#pragma unroll
  for (int i = 0; i < 8; i++) {
    const float4* q4 = (const float4*)(qp + (size_t)(b * kQ + q0 + i) * kH + lane * 8);
    qv[i][0] = q4[0]; qv[i][1] = q4[1];
  }

  const int sbase = st * 32 + wave * 8;
  const float* kbase = kp + ((size_t)b * kS + sbase) * kH + lane * 8;

  float4 k0 = *(const float4*)(kbase);
  float4 k1 = *(const float4*)(kbase + 4);

  for (int si = 0; si < 8; si++) {
    float4 n0, n1;
    if (si < 7) {
      const float* np = kbase + (size_t)(si + 1) * kH;
      n0 = *(const float4*)(np);
      n1 = *(const float4*)(np + 4);
    }
    float a[8];
#pragma unroll
    for (int i = 0; i < 8; i++) {
      float acc = 0.f, e;
      e = exp2f(qv[i][0].x + k0.x); acc = fmaf(w0.x, __builtin_amdgcn_rcpf(1.f + e), acc);
      e = exp2f(qv[i][0].y + k0.y); acc = fmaf(w0.y, __builtin_amdgcn_rcpf(1.f + e), acc);
      e = exp2f(qv[i][0].z + k0.z); acc = fmaf(w0.z, __builtin_amdgcn_rcpf(1.f + e), acc);
      e = exp2f(qv[i][0].w + k0.w); acc = fmaf(w0.w, __builtin_amdgcn_rcpf(1.f + e), acc);
      e = exp2f(qv[i][1].x + k1.x); acc = fmaf(w1.x, __builtin_amdgcn_rcpf(1.f + e), acc);
      e = exp2f(qv[i][1].y + k1.y); acc = fmaf(w1.y, __builtin_amdgcn_rcpf(1.f + e), acc);
      e = exp2f(qv[i][1].z + k1.z); acc = fmaf(w1.z, __builtin_amdgcn_rcpf(1.f + e), acc);
      e = exp2f(qv[i][1].w + k1.w); acc = fmaf(w1.w, __builtin_amdgcn_rcpf(1.f + e), acc);
      a[i] = acc;
    }
#pragma unroll
    for (int i = 0; i < 8; i++) {
#pragma unroll
      for (int off = 32; off; off >>= 1) a[i] += __shfl_xor(a[i], off);
    }
    if (lane == 0) {
      const int s = sbase + si;
#pragma unroll
      for (int i = 0; i < 8; i++)
        sout[(size_t)(b * kQ + q0 + i) * kS + s] = a[i];
    }
    k0 = n0; k1 = n1;
  }
}

// ---------------------------------------------------------------------------
// Phase 3: softmax in place on rows of 1024.  256 jobs.
// ---------------------------------------------------------------------------
__device__ __forceinline__ void softmax_phase(int row, float* sm,
                                              float* __restrict__ wout) {
  float* redm = sm;      // [4]
  float* reds = sm + 4;  // [4]
  const int t = threadIdx.x, wave = t >> 6, lane = t & 63;
  float4* rp = (float4*)(wout + (size_t)row * kS);
  float4 v = rp[t];

  float m = fmaxf(fmaxf(v.x, v.y), fmaxf(v.z, v.w));
#pragma unroll
  for (int off = 32; off; off >>= 1) m = fmaxf(m, __shfl_xor(m, off));
  if (lane == 0) redm[wave] = m;
  __syncthreads();
  m = fmaxf(fmaxf(redm[0], redm[1]), fmaxf(redm[2], redm[3]));

  float4 e;
  e.x = __expf(v.x - m); e.y = __expf(v.y - m);
  e.z = __expf(v.z - m); e.w = __expf(v.w - m);
  float sum = e.x + e.y + e.z + e.w;
#pragma unroll
  for (int off = 32; off; off >>= 1) sum += __shfl_xor(sum, off);
  if (lane == 0) reds[wave] = sum;
  __syncthreads();
  sum = reds[0] + reds[1] + reds[2] + reds[3];
  float inv = 1.f / sum;
  e.x *= inv; e.y *= inv; e.z *= inv; e.w *= inv;
  rp[t] = e;
}

// ---------------------------------------------------------------------------
// Phase 4: context partials.  512 jobs (b x 2 hc x 4 qc x 16 sc).
// part[sc][bq][h] = sum_{s in 64-chunk} w[bq][s] * value[b][s][h]
// ---------------------------------------------------------------------------
__device__ __forceinline__ void context_phase(
    int bx, float* sm, const float* __restrict__ wout,
    const float* __restrict__ value, float* __restrict__ part) {
  float (*wt)[16] = (float(*)[16])sm;  // [64][16]
  const int sc = bx & 15, qc = (bx >> 4) & 3, hc = (bx >> 6) & 1, b = bx >> 7;
  const int t = threadIdx.x;
  const int s0 = sc * 64, q0 = qc * 16;

  {  // load + transpose weights tile [16 q][64 s] -> wt[s][q]
    const int q_l = t & 15;
    const int sseg = (t >> 4) * 4;
    float4 u = *(const float4*)(wout + (size_t)(b * kQ + q0 + q_l) * kS + s0 + sseg);
    wt[sseg + 0][q_l] = u.x; wt[sseg + 1][q_l] = u.y;
    wt[sseg + 2][q_l] = u.z; wt[sseg + 3][q_l] = u.w;
  }
  __syncthreads();

  const int h = hc * 256 + t;
  const float* vb = value + ((size_t)b * kS + s0) * kH + h;
  float acc[16];
#pragma unroll
  for (int i = 0; i < 16; i++) acc[i] = 0.f;

#pragma unroll 8
  for (int s = 0; s < 64; s++) {
    float v = vb[(size_t)s * kH];
    const float4* wrow = (const float4*)&wt[s][0];
    float4 a0 = wrow[0], a1 = wrow[1], a2 = wrow[2], a3 = wrow[3];
    acc[0]  = fmaf(a0.x, v, acc[0]);  acc[1]  = fmaf(a0.y, v, acc[1]);
    acc[2]  = fmaf(a0.z, v, acc[2]);  acc[3]  = fmaf(a0.w, v, acc[3]);
    acc[4]  = fmaf(a1.x, v, acc[4]);  acc[5]  = fmaf(a1.y, v, acc[5]);
    acc[6]  = fmaf(a1.z, v, acc[6]);  acc[7]  = fmaf(a1.w, v, acc[7]);
    acc[8]  = fmaf(a2.x, v, acc[8]);  acc[9]  = fmaf(a2.y, v, acc[9]);
    acc[10] = fmaf(a2.z, v, acc[10]); acc[11] = fmaf(a2.w, v, acc[11]);
    acc[12] = fmaf(a3.x, v, acc[12]); acc[13] = fmaf(a3.y, v, acc[13]);
    acc[14] = fmaf(a3.z, v, acc[14]); acc[15] = fmaf(a3.w, v, acc[15]);
  }

  float* pp = part + (size_t)sc * kB * kQ * kH;
#pragma unroll
  for (int i = 0; i < 16; i++)
    pp[(size_t)(b * kQ + q0 + i) * kH + h] = acc[i];
}

// ---------------------------------------------------------------------------
// Phase 5: ctx[i] = sum over 16 s-chunk partials.  128 jobs.
// ---------------------------------------------------------------------------
__device__ __forceinline__ void reduce_phase(int bx,
                                             const float* __restrict__ part,
                                             float* __restrict__ ctx) {
  const int i = bx * 256 + threadIdx.x;  // float4 index, 32768 total
  float4 a = {0, 0, 0, 0};
#pragma unroll
  for (int p = 0; p < 16; p++) {
    float4 v = ((const float4*)(part + (size_t)p * kB * kQ * kH))[i];
    a.x += v.x; a.y += v.y; a.z += v.z; a.w += v.w;
  }
  ((float4*)ctx)[i] = a;
}

// ---------------------------------------------------------------------------
// Cooperative mega-kernel: grid 544 x 256.  LDS 34816B -> 4 blocks/CU cap,
// so 544 blocks are co-resident.  VGPR capped via launch_bounds(256,4).
// ---------------------------------------------------------------------------
__global__ __launch_bounds__(256, 4) void mega(
    const float* query, const float* key_, const float* value,
    const float* Wq, const float* bq, const float* Wk, const float* bk,
    const float* we, float* ctx, float* wout, float* qp, float* kp,
    float* part) {
  __shared__ __align__(16) float sm[kSmF];
  cg::grid_group grid = cg::this_grid();
  const int bx = blockIdx.x;

  proj_phase(bx, sm, key_, Wk, bk, kp, query, Wq, bq, qp);
  grid.sync();
  for (int job = bx; job < 1024; job += 544)
    score_phase(job, qp, kp, we, wout);
  grid.sync();
  if (bx < 256) softmax_phase(bx, sm, wout);
  grid.sync();
  if (bx < 512) context_phase(bx, sm, wout, value, part);
  grid.sync();
  if (bx < 128) reduce_phase(bx, part, ctx);
}

// ---- fallback wrappers (r8 pipeline) in case cooperative launch fails ----
__global__ __launch_bounds__(256, 4) void proj_k(
    const float* Xk, const float* Wk, const float* bk, float* Yk,
    const float* Xq, const float* Wq, const float* bq, float* Yq) {
  __shared__ __align__(16) float sm[kSmF];
  proj_phase(blockIdx.x, sm, Xk, Wk, bk, Yk, Xq, Wq, bq, Yq);
}
__global__ __launch_bounds__(256, 4) void score_k(
    const float* qp, const float* kp, const float* we, float* sout) {
  score_phase(blockIdx.x, qp, kp, we, sout);
}
__global__ __launch_bounds__(256, 4) void softmax_k(float* wout) {
  __shared__ float sm[8];
  softmax_phase(blockIdx.x, sm, wout);
}
__global__ __launch_bounds__(256, 4) void context_k(
    const float* wout, const float* value, float* part) {
  __shared__ __align__(16) float sm[64 * 16];
  context_phase(blockIdx.x, sm, wout, value, part);
}
__global__ __launch_bounds__(256, 4) void reduce_k(const float* part, float* ctx) {
  reduce_phase(blockIdx.x, part, ctx);
}

extern "C" void kernel_launch(void* const* d_in, const int* in_sizes, int n_in,
                              void* d_out, int out_size, void* d_ws,
                              size_t ws_size, hipStream_t stream) {
  const float* query = (const float*)d_in[0];
  const float* key_  = (const float*)d_in[1];
  const float* value = (const float*)d_in[2];
  const float* Wq    = (const float*)d_in[3];
  const float* bq    = (const float*)d_in[4];
  const float* Wk    = (const float*)d_in[5];
  const float* bk    = (const float*)d_in[6];
  const float* we    = (const float*)d_in[7];
  // be (d_in[8]) and sum(we) cancel in softmax.

  float* ctx  = (float*)d_out;                         // [256*512]
  float* wout = (float*)d_out + (size_t)kB * kQ * kH;  // [256*1024]

  float* qp   = (float*)d_ws;                          // 512 KB
  float* kp   = qp + (size_t)kB * kQ * kH;             // 8 MB
  float* part = kp;  // aliases kp (dead after score); 16*0.5 MB = 8 MB

  void* args[] = {(void*)&query, (void*)&key_, (void*)&value, (void*)&Wq,
                  (void*)&bq,    (void*)&Wk,   (void*)&bk,    (void*)&we,
                  (void*)&ctx,   (void*)&wout, (void*)&qp,    (void*)&kp,
                  (void*)&part};
  hipError_t err = hipLaunchCooperativeKernel(
      (void*)mega, dim3(544), dim3(256), args, 0, stream);
  if (err != hipSuccess) {
    (void)hipGetLastError();  // clear sticky error; use 5-kernel fallback
    proj_k<<<544, 256, 0, stream>>>(key_, Wk, bk, kp, query, Wq, bq, qp);
    score_k<<<1024, 256, 0, stream>>>(qp, kp, we, wout);
    softmax_k<<<256, 256, 0, stream>>>(wout);
    context_k<<<512, 256, 0, stream>>>(wout, value, part);
    reduce_k<<<128, 256, 0, stream>>>(part, ctx);
  }
}